// Round 4
// baseline (408.340 us; speedup 1.0000x reference)
//
#include <hip/hip_runtime.h>
#include <hip/hip_bf16.h>

typedef __attribute__((ext_vector_type(8))) short short8;
typedef float floatx4 __attribute__((ext_vector_type(4)));

#define LQ 4096
#define LK 1024
#define NH 24
#define HD 128
#define HID 3072

__device__ __forceinline__ unsigned short f2bf(float f) {
    __hip_bfloat16 h = __float2bfloat16(f);
    union { __hip_bfloat16 b; unsigned short u; } c; c.b = h;
    return c.u;
}

// async global->LDS, 16B per lane. LDS dest must be wave-uniform base (HW adds lane*16).
__device__ __forceinline__ void gload16(const void* g, void* l) {
    __builtin_amdgcn_global_load_lds(
        (const __attribute__((address_space(1))) void*)g,
        (__attribute__((address_space(3))) void*)l,
        16, 0, 0);
}

// ---------------- f32 -> bf16 convert ----------------
__global__ void f32_to_bf16(const float* __restrict__ in, unsigned short* __restrict__ out, int n4) {
    int i = blockIdx.x * blockDim.x + threadIdx.x;
    int stride = gridDim.x * blockDim.x;
    for (; i < n4; i += stride) {
        float4 v = ((const float4*)in)[i];
        ushort4 o;
        o.x = f2bf(v.x); o.y = f2bf(v.y); o.z = f2bf(v.z); o.w = f2bf(v.w);
        ((ushort4*)out)[i] = o;
    }
}

// ---------------- bf16 GEMM: C[m][n] = sum_k A[m][k] * B[n][k] ----------------
// BM=64, BN=128, BK=64. global_load_lds staging (linear dest, source-XOR-swizzled),
// double-buffered, ONE barrier per K-step. XCD swizzle: each XCD owns 3 n-panels.
__global__ __launch_bounds__(256) void gemm_proj(const unsigned short* __restrict__ A,
                                                 const unsigned short* __restrict__ Bw,
                                                 float* __restrict__ C,
                                                 int M, int N, int K) {
    __shared__ __align__(16) unsigned short As[2][64 * 64];
    __shared__ __align__(16) unsigned short Bs[2][128 * 64];
    const int tid = threadIdx.x;
    const int lane = tid & 63;
    const int wave = tid >> 6;
    const int wm = wave >> 1, wn = wave & 1;
    // XCD-aware remap: flat 0..383 -> each XCD gets a contiguous chunk of n-panels
    const int flat = blockIdx.x + gridDim.x * blockIdx.y;  // gridDim.x = 16, 384 total
    const int wid = (flat & 7) * 48 + (flat >> 3);
    const int bm0 = (wid & 15) * 64;
    const int bn0 = (wid >> 4) * 128;
    const int lr = lane & 15;
    const int lg = lane >> 4;

    floatx4 acc[2][4];
    for (int i = 0; i < 2; ++i)
        for (int j = 0; j < 4; ++j)
            acc[i][j] = (floatx4){0.f, 0.f, 0.f, 0.f};

    auto stage = [&](int b, int k0) {
        for (int p = 0; p < 2; ++p) {
            int slot = p * 256 + tid;
            int r = slot >> 3, cb = slot & 7;
            int g = cb ^ (r & 7);
            gload16(&A[(bm0 + r) * K + k0 + g * 8], &As[b][(p * 256 + wave * 64) * 8]);
        }
        for (int p = 0; p < 4; ++p) {
            int slot = p * 256 + tid;
            int r = slot >> 3, cb = slot & 7;
            int g = cb ^ (r & 7);
            gload16(&Bw[(bn0 + r) * K + k0 + g * 8], &Bs[b][(p * 256 + wave * 64) * 8]);
        }
    };

    auto compute = [&](int b) {
        for (int ks = 0; ks < 2; ++ks) {
            short8 af[2], bfr[4];
            for (int mt = 0; mt < 2; ++mt) {
                int m = wm * 32 + mt * 16 + lr;
                int sc = (ks * 4 + lg) ^ (m & 7);
                af[mt] = *(const short8*)(&As[b][m * 64 + sc * 8]);
            }
            for (int nt = 0; nt < 4; ++nt) {
                int n = wn * 64 + nt * 16 + lr;
                int sc = (ks * 4 + lg) ^ (n & 7);
                bfr[nt] = *(const short8*)(&Bs[b][n * 64 + sc * 8]);
            }
            for (int mt = 0; mt < 2; ++mt)
                for (int nt = 0; nt < 4; ++nt)
                    acc[mt][nt] = __builtin_amdgcn_mfma_f32_16x16x32_bf16(af[mt], bfr[nt], acc[mt][nt], 0, 0, 0);
        }
    };

    stage(0, 0);
    __syncthreads();
    int buf = 0;
    for (int k0 = 0; k0 < K - 64; k0 += 64) {
        stage(buf ^ 1, k0 + 64);
        compute(buf);
        __syncthreads();
        buf ^= 1;
    }
    compute(buf);

    for (int mt = 0; mt < 2; ++mt)
        for (int nt = 0; nt < 4; ++nt)
            for (int rg = 0; rg < 4; ++rg) {
                int m = bm0 + wm * 32 + mt * 16 + lg * 4 + rg;
                int n = bn0 + wn * 64 + nt * 16 + lr;
                C[m * N + n] = acc[mt][nt][rg];
            }
}

// ---------------- RMSNorm + RoPE on K ----------------
__global__ __launch_bounds__(128) void rmsnorm_rope(const float* __restrict__ Kraw,
                                                    const float* __restrict__ freqs,
                                                    const float* __restrict__ w,
                                                    unsigned short* __restrict__ Kbf) {
    int bid = blockIdx.x;
    int l = bid / NH, h = bid % NH;
    int d = threadIdx.x;
    float x = Kraw[l * HID + h * HD + d];
    float ss = x * x;
    for (int off = 32; off; off >>= 1) ss += __shfl_xor(ss, off);
    __shared__ float red[2];
    int wid = d >> 6;
    if ((d & 63) == 0) red[wid] = ss;
    __syncthreads();
    float tot = red[0] + red[1];
    float rsn = rsqrtf(tot * (1.0f / 128.0f) + 1e-6f);
    float xn = x * rsn * w[d];
    float f = freqs[l * (HD / 2) + (d >> 1)];
    float s, c;
    sincosf(f, &s, &c);
    float partner = __shfl_xor(xn, 1);
    float o = (d & 1) ? (partner * s + xn * c) : (xn * c - partner * s);
    Kbf[l * HID + h * HD + d] = f2bf(o);
}

// ---------------- V transpose: Vraw[l][hd] f32 -> Vt[hd][l] bf16 ----------------
__global__ __launch_bounds__(256) void transpose_v(const float* __restrict__ Vraw,
                                                   unsigned short* __restrict__ Vt) {
    __shared__ float tile[32][33];
    int bx = blockIdx.x;
    int by = blockIdx.y;
    int tx = threadIdx.x & 31, ty = threadIdx.x >> 5;
    int c0 = bx * 32, r0 = by * 32;
    for (int i = 0; i < 4; ++i) {
        int r = ty + i * 8;
        tile[r][tx] = Vraw[(r0 + r) * HID + c0 + tx];
    }
    __syncthreads();
    for (int i = 0; i < 4; ++i) {
        int rr = ty + i * 8;
        Vt[(c0 + rr) * LK + r0 + tx] = f2bf(tile[tx][rr]);
    }
}

// ---------------- Flash attention ----------------
// grid = 768 blocks (3/CU exactly), 256 threads = 4 waves, wave owns 32 q-rows.
// K staged into double-buffered LDS (gload_lds, source-XOR-swizzled), one barrier
// per tile. V read straight from global (same 16KB tile for all 4 barrier-clustered
// waves -> L1/L2 hits; XCD swizzle keeps each XCD's 3 heads L2-resident).
// Fixed-shift softmax, deferred row-sum. LDS 48KB -> 3 blocks/CU.
__global__ __launch_bounds__(256, 3) void attn(const float* __restrict__ Q,
                                               const unsigned short* __restrict__ Kbf,
                                               const unsigned short* __restrict__ Vt,
                                               float* __restrict__ O) {
    __shared__ __align__(16) unsigned short Ks[2][64 * 128];   // [key][d], 16 blocks/row, swizzled
    __shared__ __align__(16) unsigned short Plds[4][32 * 64];  // per-wave P, 8 blocks/row, swizzled
    const int tid = threadIdx.x;
    const int lane = tid & 63;
    const int wave = tid >> 6;
    const int lr = lane & 15, lg = lane >> 4;
    // XCD-aware remap: flat 0..767, XCD = flat%8 owns heads 3k..3k+2
    const int flat = blockIdx.x + gridDim.x * blockIdx.y;  // gridDim.x = 32
    const int wid = (flat & 7) * 96 + (flat >> 3);
    const int h = wid >> 5;
    const int q0 = (wid & 31) * 128 + wave * 32;
    const float qscale = 0.08838834764831843f * 1.44269504088896340736f;  // D^-0.5 * log2(e)
    const float SHIFT = 32.0f;

    short8 qf[2][4];
    for (int mt = 0; mt < 2; ++mt)
        for (int ks = 0; ks < 4; ++ks) {
            const float* qp = &Q[(q0 + mt * 16 + lr) * HID + h * HD + ks * 32 + lg * 8];
            float4 lo = *(const float4*)(qp);
            float4 hi = *(const float4*)(qp + 4);
            short8 v;
            v[0] = (short)f2bf(lo.x * qscale);
            v[1] = (short)f2bf(lo.y * qscale);
            v[2] = (short)f2bf(lo.z * qscale);
            v[3] = (short)f2bf(lo.w * qscale);
            v[4] = (short)f2bf(hi.x * qscale);
            v[5] = (short)f2bf(hi.y * qscale);
            v[6] = (short)f2bf(hi.z * qscale);
            v[7] = (short)f2bf(hi.w * qscale);
            qf[mt][ks] = v;
        }

    floatx4 accO[2][8];
    for (int mt = 0; mt < 2; ++mt)
        for (int i = 0; i < 8; ++i) accO[mt][i] = (floatx4){0.f, 0.f, 0.f, 0.f};
    float psum[2][4] = {{0.f, 0.f, 0.f, 0.f}, {0.f, 0.f, 0.f, 0.f}};
    unsigned short* Pw = &Plds[wave][0];

    // cooperative K staging (issue-only)
    auto stage = [&](int b, int kt) {
        for (int i = 0; i < 4; ++i) {
            int slot = i * 256 + tid;
            int r = slot >> 4, bb = slot & 15;
            int g = bb ^ (r & 15);
            gload16(&Kbf[(kt * 64 + r) * HID + h * HD + g * 8],
                    &Ks[b][(i * 256 + wave * 64) * 8]);
        }
    };

    auto compute = [&](int b, int kt) {
        floatx4 sa[2][4];
        for (int mt = 0; mt < 2; ++mt)
            for (int nt = 0; nt < 4; ++nt)
                sa[mt][nt] = (floatx4){-SHIFT, -SHIFT, -SHIFT, -SHIFT};
        for (int ks = 0; ks < 4; ++ks)
            for (int nt = 0; nt < 4; ++nt) {
                int key = nt * 16 + lr;
                int pb = (ks * 4 + lg) ^ (key & 15);
                short8 kf = *(const short8*)(&Ks[b][key * 128 + pb * 8]);
                sa[0][nt] = __builtin_amdgcn_mfma_f32_16x16x32_bf16(qf[0][ks], kf, sa[0][nt], 0, 0, 0);
                sa[1][nt] = __builtin_amdgcn_mfma_f32_16x16x32_bf16(qf[1][ks], kf, sa[1][nt], 0, 0, 0);
            }
        for (int mt = 0; mt < 2; ++mt)
            for (int nt = 0; nt < 4; ++nt)
                for (int rg = 0; rg < 4; ++rg) {
                    float p = exp2f(sa[mt][nt][rg]);
                    psum[mt][rg] += p;
                    int row = mt * 16 + lg * 4 + rg;
                    int col = nt * 16 + lr;
                    int sw = (col >> 3) ^ (row & 7);
                    Pw[row * 64 + sw * 8 + (col & 7)] = f2bf(p);
                }
        // O += P V  (V straight from global; all 4 waves hit the same L1-resident tile)
        for (int ks2 = 0; ks2 < 2; ++ks2) {
            int pbs = (ks2 * 4 + lg) ^ (lr & 7);
            short8 pf0 = *(const short8*)(&Pw[lr * 64 + pbs * 8]);
            short8 pf1 = *(const short8*)(&Pw[(16 + lr) * 64 + pbs * 8]);
            for (int ntd = 0; ntd < 8; ++ntd) {
                short8 vf = *(const short8*)(&Vt[(h * HD + ntd * 16 + lr) * LK + kt * 64 + ks2 * 32 + lg * 8]);
                accO[0][ntd] = __builtin_amdgcn_mfma_f32_16x16x32_bf16(pf0, vf, accO[0][ntd], 0, 0, 0);
                accO[1][ntd] = __builtin_amdgcn_mfma_f32_16x16x32_bf16(pf1, vf, accO[1][ntd], 0, 0, 0);
            }
        }
    };

    stage(0, 0);
    __syncthreads();
    int buf = 0;
    for (int kt = 0; kt < LK / 64 - 1; ++kt) {
        stage(buf ^ 1, kt + 1);
        compute(buf, kt);
        __syncthreads();
        buf ^= 1;
    }
    compute(buf, LK / 64 - 1);

    float rinv[2][4];
    for (int mt = 0; mt < 2; ++mt)
        for (int rg = 0; rg < 4; ++rg) {
            float s = psum[mt][rg];
            for (int off = 1; off <= 8; off <<= 1) s += __shfl_xor(s, off);
            rinv[mt][rg] = 1.0f / s;
        }
    for (int mt = 0; mt < 2; ++mt)
        for (int ntd = 0; ntd < 8; ++ntd)
            for (int rg = 0; rg < 4; ++rg) {
                int q = q0 + mt * 16 + lg * 4 + rg;
                O[q * HID + h * HD + ntd * 16 + lr] = accO[mt][ntd][rg] * rinv[mt][rg];
            }
}

extern "C" void kernel_launch(void* const* d_in, const int* in_sizes, int n_in,
                              void* d_out, int out_size, void* d_ws, size_t ws_size,
                              hipStream_t stream) {
    const float* Q      = (const float*)d_in[0];
    const float* latent = (const float*)d_in[1];
    const float* freqs  = (const float*)d_in[2];
    const float* Wk     = (const float*)d_in[3];
    const float* Wv     = (const float*)d_in[4];
    const float* rmsw   = (const float*)d_in[5];
    float* out = (float*)d_out;
    char* ws = (char*)d_ws;

    unsigned short* latent_bf = (unsigned short*)(ws);                  //  6,291,456
    unsigned short* Wk_bf     = (unsigned short*)(ws + 6291456);        // 18,874,368
    unsigned short* Wv_bf     = (unsigned short*)(ws + 25165824);       // 18,874,368
    float*          raw       = (float*)(ws + 44040192);                // 12,582,912 (shared K then V)
    unsigned short* Kbf       = (unsigned short*)(ws + 56623104);       //  6,291,456
    unsigned short* Vt        = (unsigned short*)(ws + 62914560);       //  6,291,456

    f32_to_bf16<<<2048, 256, 0, stream>>>(latent, latent_bf, (LK * HID) / 4);
    f32_to_bf16<<<2048, 256, 0, stream>>>(Wk, Wk_bf, (HID * HID) / 4);
    f32_to_bf16<<<2048, 256, 0, stream>>>(Wv, Wv_bf, (HID * HID) / 4);

    gemm_proj<<<dim3(16, 24), 256, 0, stream>>>(latent_bf, Wk_bf, raw, LK, HID, HID);
    rmsnorm_rope<<<LK * NH, 128, 0, stream>>>(raw, freqs, rmsw, Kbf);
    gemm_proj<<<dim3(16, 24), 256, 0, stream>>>(latent_bf, Wv_bf, raw, LK, HID, HID);
    transpose_v<<<dim3(HID / 32, LK / 32), 256, 0, stream>>>(raw, Vt);

    attn<<<dim3(LQ / 128, NH), 256, 0, stream>>>(Q, Kbf, Vt, out);
}

// Round 5
// 214.736 us; speedup vs baseline: 1.9016x; 1.9016x over previous
//
#include <hip/hip_runtime.h>
#include <hip/hip_bf16.h>

typedef __attribute__((ext_vector_type(8))) short short8;
typedef float floatx4 __attribute__((ext_vector_type(4)));

#define LQ 4096
#define LK 1024
#define NH 24
#define HD 128
#define HID 3072

__device__ __forceinline__ unsigned short f2bf(float f) {
    __hip_bfloat16 h = __float2bfloat16(f);
    union { __hip_bfloat16 b; unsigned short u; } c; c.b = h;
    return c.u;
}

// async global->LDS, 16B per lane. LDS dest must be wave-uniform base (HW adds lane*16).
__device__ __forceinline__ void gload16(const void* g, void* l) {
    __builtin_amdgcn_global_load_lds(
        (const __attribute__((address_space(1))) void*)g,
        (__attribute__((address_space(3))) void*)l,
        16, 0, 0);
}

// ---------------- f32 -> bf16 convert ----------------
__global__ void f32_to_bf16(const float* __restrict__ in, unsigned short* __restrict__ out, int n4) {
    int i = blockIdx.x * blockDim.x + threadIdx.x;
    int stride = gridDim.x * blockDim.x;
    for (; i < n4; i += stride) {
        float4 v = ((const float4*)in)[i];
        ushort4 o;
        o.x = f2bf(v.x); o.y = f2bf(v.y); o.z = f2bf(v.z); o.w = f2bf(v.w);
        ((ushort4*)out)[i] = o;
    }
}

// ---------------- bf16 GEMM with fused B-conversion ----------------
// C[m][n] = sum_k A[m][k](bf16) * Bf[n][k](f32, converted in-register).
// BM=64, BN=128, BK=64. A via global_load_lds (source-XOR-swizzled, linear dest);
// B reg-staged: f32 load -> cvt bf16 -> swizzled ds_write. Double-buffered,
// one barrier per K-step. XCD swizzle: each XCD owns 3 n-panels.
__global__ __launch_bounds__(256) void gemm_proj(const unsigned short* __restrict__ A,
                                                 const float* __restrict__ Bf,
                                                 float* __restrict__ C,
                                                 int M, int N, int K) {
    __shared__ __align__(16) unsigned short As[2][64 * 64];
    __shared__ __align__(16) unsigned short Bs[2][128 * 64];
    const int tid = threadIdx.x;
    const int lane = tid & 63;
    const int wave = tid >> 6;
    const int wm = wave >> 1, wn = wave & 1;
    const int flat = blockIdx.x + gridDim.x * blockIdx.y;  // gridDim.x=16, 384 total
    const int wid = (flat & 7) * 48 + (flat >> 3);
    const int bm0 = (wid & 15) * 64;
    const int bn0 = (wid >> 4) * 128;
    const int lr = lane & 15;
    const int lg = lane >> 4;

    floatx4 acc[2][4];
    for (int i = 0; i < 2; ++i)
        for (int j = 0; j < 4; ++j)
            acc[i][j] = (floatx4){0.f, 0.f, 0.f, 0.f};

    auto stage = [&](int b, int k0) {
        // A: 64 rows x 8 blocks of 16B, linear dest, source-swizzled
        for (int p = 0; p < 2; ++p) {
            int slot = p * 256 + tid;
            int r = slot >> 3, cb = slot & 7;
            int g = cb ^ (r & 7);
            gload16(&A[(bm0 + r) * K + k0 + g * 8], &As[b][(p * 256 + wave * 64) * 8]);
        }
        // B: 128 rows; read f32, convert, write swizzled (write-side swizzle OK: reg-staged)
        for (int p = 0; p < 4; ++p) {
            int slot = p * 256 + tid;
            int r = slot >> 3, cb = slot & 7;
            int sc = cb ^ (r & 7);
            const float* bp = &Bf[(bn0 + r) * K + k0 + cb * 8];
            float4 lo = *(const float4*)(bp);
            float4 hi = *(const float4*)(bp + 4);
            short8 v;
            v[0] = (short)f2bf(lo.x); v[1] = (short)f2bf(lo.y);
            v[2] = (short)f2bf(lo.z); v[3] = (short)f2bf(lo.w);
            v[4] = (short)f2bf(hi.x); v[5] = (short)f2bf(hi.y);
            v[6] = (short)f2bf(hi.z); v[7] = (short)f2bf(hi.w);
            *(short8*)(&Bs[b][r * 64 + sc * 8]) = v;
        }
    };

    auto compute = [&](int b) {
        for (int ks = 0; ks < 2; ++ks) {
            short8 af[2], bfr[4];
            for (int mt = 0; mt < 2; ++mt) {
                int m = wm * 32 + mt * 16 + lr;
                int sc = (ks * 4 + lg) ^ (m & 7);
                af[mt] = *(const short8*)(&As[b][m * 64 + sc * 8]);
            }
            for (int nt = 0; nt < 4; ++nt) {
                int n = wn * 64 + nt * 16 + lr;
                int sc = (ks * 4 + lg) ^ (n & 7);
                bfr[nt] = *(const short8*)(&Bs[b][n * 64 + sc * 8]);
            }
            for (int mt = 0; mt < 2; ++mt)
                for (int nt = 0; nt < 4; ++nt)
                    acc[mt][nt] = __builtin_amdgcn_mfma_f32_16x16x32_bf16(af[mt], bfr[nt], acc[mt][nt], 0, 0, 0);
        }
    };

    stage(0, 0);
    __syncthreads();
    int buf = 0;
    for (int k0 = 0; k0 < K - 64; k0 += 64) {
        stage(buf ^ 1, k0 + 64);
        compute(buf);
        __syncthreads();
        buf ^= 1;
    }
    compute(buf);

    for (int mt = 0; mt < 2; ++mt)
        for (int nt = 0; nt < 4; ++nt)
            for (int rg = 0; rg < 4; ++rg) {
                int m = bm0 + wm * 32 + mt * 16 + lg * 4 + rg;
                int n = bn0 + wn * 64 + nt * 16 + lr;
                C[m * N + n] = acc[mt][nt][rg];
            }
}

// ---------------- RMSNorm + RoPE on K ----------------
__global__ __launch_bounds__(128) void rmsnorm_rope(const float* __restrict__ Kraw,
                                                    const float* __restrict__ freqs,
                                                    const float* __restrict__ w,
                                                    unsigned short* __restrict__ Kbf) {
    int bid = blockIdx.x;
    int l = bid / NH, h = bid % NH;
    int d = threadIdx.x;
    float x = Kraw[l * HID + h * HD + d];
    float ss = x * x;
    for (int off = 32; off; off >>= 1) ss += __shfl_xor(ss, off);
    __shared__ float red[2];
    int wid = d >> 6;
    if ((d & 63) == 0) red[wid] = ss;
    __syncthreads();
    float tot = red[0] + red[1];
    float rsn = rsqrtf(tot * (1.0f / 128.0f) + 1e-6f);
    float xn = x * rsn * w[d];
    float f = freqs[l * (HD / 2) + (d >> 1)];
    float s, c;
    sincosf(f, &s, &c);
    float partner = __shfl_xor(xn, 1);
    float o = (d & 1) ? (partner * s + xn * c) : (xn * c - partner * s);
    Kbf[l * HID + h * HD + d] = f2bf(o);
}

// ---------------- V transpose: Vraw[l][hd] f32 -> Vt[hd][l] bf16 ----------------
__global__ __launch_bounds__(256) void transpose_v(const float* __restrict__ Vraw,
                                                   unsigned short* __restrict__ Vt) {
    __shared__ float tile[32][33];
    int bx = blockIdx.x;
    int by = blockIdx.y;
    int tx = threadIdx.x & 31, ty = threadIdx.x >> 5;
    int c0 = bx * 32, r0 = by * 32;
    for (int i = 0; i < 4; ++i) {
        int r = ty + i * 8;
        tile[r][tx] = Vraw[(r0 + r) * HID + c0 + tx];
    }
    __syncthreads();
    for (int i = 0; i < 4; ++i) {
        int rr = ty + i * 8;
        Vt[(c0 + rr) * LK + r0 + tx] = f2bf(tile[tx][rr]);
    }
}

// ---------------- Flash attention ----------------
// Round-3 dataflow (K AND V staged through LDS; 74MB FETCH proven) with KVBLK=32:
// LDS = K dbuf 16K + V dbuf 16K + P 8K = 40KB -> 4 blocks/CU by LDS; grid 768
// fully co-resident (no tail round). 4 waves/block, wave owns 32 q-rows (M_rep=2).
// Double-buffered, one barrier per tile; stage issued before compute (loads in
// flight under compute). Fixed-shift softmax, deferred row-sum. XCD swizzle:
// 3 heads/XCD -> K/V L2-resident.
__global__ __launch_bounds__(256, 3) void attn(const float* __restrict__ Q,
                                               const unsigned short* __restrict__ Kbf,
                                               const unsigned short* __restrict__ Vt,
                                               float* __restrict__ O) {
    __shared__ __align__(16) unsigned short Ks[2][32 * 128];   // [key][d], 16 blocks/row, src-swizzled
    __shared__ __align__(16) unsigned short Vs[2][128 * 32];   // [hd][l], 4 blocks/row, src-swizzled
    __shared__ __align__(16) unsigned short Plds[4][32 * 32];  // per-wave P, 4 blocks/row, swizzled
    const int tid = threadIdx.x;
    const int lane = tid & 63;
    const int wave = tid >> 6;
    const int lr = lane & 15, lg = lane >> 4;
    const int flat = blockIdx.x + gridDim.x * blockIdx.y;  // gridDim.x = 32
    const int wid = (flat & 7) * 96 + (flat >> 3);          // bijective: 768 = 8*96
    const int h = wid >> 5;
    const int q0 = (wid & 31) * 128 + wave * 32;
    const float qscale = 0.08838834764831843f * 1.44269504088896340736f;  // D^-0.5 * log2(e)
    const float SHIFT = 32.0f;

    short8 qf[2][4];
    for (int mt = 0; mt < 2; ++mt)
        for (int ks = 0; ks < 4; ++ks) {
            const float* qp = &Q[(q0 + mt * 16 + lr) * HID + h * HD + ks * 32 + lg * 8];
            float4 lo = *(const float4*)(qp);
            float4 hi = *(const float4*)(qp + 4);
            short8 v;
            v[0] = (short)f2bf(lo.x * qscale);
            v[1] = (short)f2bf(lo.y * qscale);
            v[2] = (short)f2bf(lo.z * qscale);
            v[3] = (short)f2bf(lo.w * qscale);
            v[4] = (short)f2bf(hi.x * qscale);
            v[5] = (short)f2bf(hi.y * qscale);
            v[6] = (short)f2bf(hi.z * qscale);
            v[7] = (short)f2bf(hi.w * qscale);
            qf[mt][ks] = v;
        }

    floatx4 accO[2][8];
    for (int mt = 0; mt < 2; ++mt)
        for (int i = 0; i < 8; ++i) accO[mt][i] = (floatx4){0.f, 0.f, 0.f, 0.f};
    float psum[2][4] = {{0.f, 0.f, 0.f, 0.f}, {0.f, 0.f, 0.f, 0.f}};
    unsigned short* Pw = &Plds[wave][0];

    // cooperative staging of kv-tile kt (32 keys): 2 K + 2 V gload16 per thread
    auto stage = [&](int b, int kt) {
        for (int i = 0; i < 2; ++i) {
            int slot = i * 256 + tid;             // 512 slots = 32 rows x 16 blocks
            int r = slot >> 4, bb = slot & 15;
            int g = bb ^ (r & 15);
            gload16(&Kbf[(kt * 32 + r) * HID + h * HD + g * 8],
                    &Ks[b][(i * 256 + wave * 64) * 8]);
        }
        for (int i = 0; i < 2; ++i) {
            int slot = i * 256 + tid;             // 512 slots = 128 rows x 4 blocks
            int rv = slot >> 2, bv = slot & 3;
            int gv = bv ^ (rv & 3);
            gload16(&Vt[(h * HD + rv) * LK + kt * 32 + gv * 8],
                    &Vs[b][(i * 256 + wave * 64) * 8]);
        }
    };

    auto compute = [&](int b) {
        floatx4 sa[2][2];
        for (int mt = 0; mt < 2; ++mt)
            for (int nt = 0; nt < 2; ++nt)
                sa[mt][nt] = (floatx4){-SHIFT, -SHIFT, -SHIFT, -SHIFT};
        for (int ks = 0; ks < 4; ++ks)
            for (int nt = 0; nt < 2; ++nt) {
                int key = nt * 16 + lr;
                int pb = (ks * 4 + lg) ^ (key & 15);
                short8 kf = *(const short8*)(&Ks[b][key * 128 + pb * 8]);
                sa[0][nt] = __builtin_amdgcn_mfma_f32_16x16x32_bf16(qf[0][ks], kf, sa[0][nt], 0, 0, 0);
                sa[1][nt] = __builtin_amdgcn_mfma_f32_16x16x32_bf16(qf[1][ks], kf, sa[1][nt], 0, 0, 0);
            }
        // P = exp2(S - SHIFT); partial row sums; P -> LDS (bf16, swizzled)
        for (int mt = 0; mt < 2; ++mt)
            for (int nt = 0; nt < 2; ++nt)
                for (int rg = 0; rg < 4; ++rg) {
                    float p = exp2f(sa[mt][nt][rg]);
                    psum[mt][rg] += p;
                    int row = mt * 16 + lg * 4 + rg;
                    int col = nt * 16 + lr;
                    int sw = (col >> 3) ^ (row & 3);
                    Pw[row * 32 + sw * 8 + (col & 7)] = f2bf(p);
                }
        // O += P V  (single 32-k chunk)
        short8 pf[2];
        for (int mt = 0; mt < 2; ++mt) {
            int prow = mt * 16 + lr;
            int psw = lg ^ (prow & 3);
            pf[mt] = *(const short8*)(&Pw[prow * 32 + psw * 8]);
        }
        for (int ntd = 0; ntd < 8; ++ntd) {
            int hd = ntd * 16 + lr;
            int vb = lg ^ (hd & 3);
            short8 vf = *(const short8*)(&Vs[b][hd * 32 + vb * 8]);
            accO[0][ntd] = __builtin_amdgcn_mfma_f32_16x16x32_bf16(pf[0], vf, accO[0][ntd], 0, 0, 0);
            accO[1][ntd] = __builtin_amdgcn_mfma_f32_16x16x32_bf16(pf[1], vf, accO[1][ntd], 0, 0, 0);
        }
    };

    stage(0, 0);
    __syncthreads();
    int buf = 0;
    for (int kt = 0; kt < LK / 32 - 1; ++kt) {
        stage(buf ^ 1, kt + 1);
        compute(buf);
        __syncthreads();
        buf ^= 1;
    }
    compute(buf);

    float rinv[2][4];
    for (int mt = 0; mt < 2; ++mt)
        for (int rg = 0; rg < 4; ++rg) {
            float s = psum[mt][rg];
            for (int off = 1; off <= 8; off <<= 1) s += __shfl_xor(s, off);
            rinv[mt][rg] = 1.0f / s;
        }
    for (int mt = 0; mt < 2; ++mt)
        for (int ntd = 0; ntd < 8; ++ntd)
            for (int rg = 0; rg < 4; ++rg) {
                int q = q0 + mt * 16 + lg * 4 + rg;
                O[q * HID + h * HD + ntd * 16 + lr] = accO[mt][ntd][rg] * rinv[mt][rg];
            }
}

extern "C" void kernel_launch(void* const* d_in, const int* in_sizes, int n_in,
                              void* d_out, int out_size, void* d_ws, size_t ws_size,
                              hipStream_t stream) {
    const float* Q      = (const float*)d_in[0];
    const float* latent = (const float*)d_in[1];
    const float* freqs  = (const float*)d_in[2];
    const float* Wk     = (const float*)d_in[3];
    const float* Wv     = (const float*)d_in[4];
    const float* rmsw   = (const float*)d_in[5];
    float* out = (float*)d_out;
    char* ws = (char*)d_ws;

    unsigned short* latent_bf = (unsigned short*)(ws);                  //  6,291,456
    float*          raw       = (float*)(ws + 6291456);                 // 12,582,912 (K then V)
    unsigned short* Kbf       = (unsigned short*)(ws + 18874368);       //  6,291,456
    unsigned short* Vt        = (unsigned short*)(ws + 25165824);       //  6,291,456

    f32_to_bf16<<<2048, 256, 0, stream>>>(latent, latent_bf, (LK * HID) / 4);

    gemm_proj<<<dim3(16, 24), 256, 0, stream>>>(latent_bf, Wk, raw, LK, HID, HID);
    rmsnorm_rope<<<LK * NH, 128, 0, stream>>>(raw, freqs, rmsw, Kbf);
    gemm_proj<<<dim3(16, 24), 256, 0, stream>>>(latent_bf, Wv, raw, LK, HID, HID);
    transpose_v<<<dim3(HID / 32, LK / 32), 256, 0, stream>>>(raw, Vt);

    attn<<<dim3(LQ / 128, NH), 256, 0, stream>>>(Q, Kbf, Vt, out);
}